// Round 15
// baseline (210.272 us; speedup 1.0000x reference)
//
#include <hip/hip_runtime.h>
#include <hip/hip_bf16.h>
#include <math.h>

typedef __bf16 bf16_t;
typedef __attribute__((ext_vector_type(8))) __bf16 bf16x8;
typedef __attribute__((ext_vector_type(4))) __bf16 bf16x4;
typedef __attribute__((ext_vector_type(4))) short s16x4;
typedef __attribute__((ext_vector_type(4))) float f32x4;

#define AS1C(p) ((const __attribute__((address_space(1))) void*)(p))
#define AS3(p)  ((__attribute__((address_space(3))) void*)(p))

__device__ __forceinline__ float fast_exp2(float x) { return __builtin_amdgcn_exp2f(x); }

// ------------- transpose+convert body: in (R x C f32) -> out (C x R bf16) -------------
__device__ __forceinline__ void tconv_body(const float* __restrict__ in,
                                           bf16_t* __restrict__ out, int R, int C,
                                           int r0, int c0, float (*tile)[65], int tid) {
#pragma unroll
    for (int i = 0; i < 16; ++i) {
        int e = i * 256 + tid;
        int r = e >> 6, c = e & 63;
        tile[r][c] = in[(size_t)(r0 + r) * C + c0 + c];
    }
    __syncthreads();
#pragma unroll
    for (int i = 0; i < 16; ++i) {
        int e = i * 256 + tid;
        int c = e >> 6, r = e & 63;
        out[(size_t)(c0 + c) * R + r0 + r] = (bf16_t)tile[r][c];
    }
}

// ---------------- fused prep: cvt(x) | tconv(wqkv) | tconv(wproj) | RoPE tables ----------
__global__ __launch_bounds__(256) void k_prep(const float* __restrict__ x,
                                              const float* __restrict__ wqkv,
                                              const float* __restrict__ wproj,
                                              bf16_t* __restrict__ xb,
                                              bf16_t* __restrict__ wqT,
                                              bf16_t* __restrict__ wpT,
                                              float* __restrict__ cosT,
                                              float* __restrict__ sinT) {
    __shared__ float tile[64][65];
    const int bid = blockIdx.x, tid = threadIdx.x;
    if (bid < 8192) {
        int i = bid * 256 + tid;
        float4 v = reinterpret_cast<const float4*>(x)[i];
        bf16x4 o;
        o[0] = (bf16_t)v.x; o[1] = (bf16_t)v.y; o[2] = (bf16_t)v.z; o[3] = (bf16_t)v.w;
        reinterpret_cast<bf16x4*>(xb)[i] = o;
    } else if (bid < 8960) {
        int t = bid - 8192;                    // 768 = 48 cx * 16 ry
        tconv_body(wqkv, wqT, 1024, 3072, (t / 48) * 64, (t % 48) * 64, tile, tid);
    } else if (bid < 9216) {
        int t = bid - 8960;                    // 256 = 16 cx * 16 ry
        tconv_body(wproj, wpT, 1024, 1024, (t / 16) * 64, (t % 16) * 64, tile, tid);
    } else {
        int i = (bid - 9216) * 256 + tid;      // 65536 table entries
        int l = i >> 6, d = i & 63;
        int hh = l >> 5, ww = l & 31;          // H = W = 32
        float pos = (d < 32) ? (-1.0f + (2.0f / 31.0f) * (float)hh)
                             : (-1.0f + (2.0f / 31.0f) * (float)ww);
        int fi = (d & 31) >> 1;
        float fb = (1.0f + (127.0f / 15.0f) * (float)fi) * 3.14159265358979323846f;
        float fr = pos * fb;
        cosT[i] = cosf(fr);
        sinT[i] = sinf(fr);
    }
}

// ---------------- 128x128 double-buffered pipelined GEMM core (K=1024) ----------------
// 4 waves (2M x 2N), per-wave 64x64 (acc[4][4]). 64 KiB LDS -> 2 blocks/CU.
// Counted vmcnt(8) depth-1 prefetch, 2 barriers/tile, T2 swizzle (conflict-free reads).
__device__ __forceinline__ void gemm128_pipe(const bf16_t* __restrict__ A,
                                             const bf16_t* __restrict__ Bt,
                                             int rowA0, int colB0, int w, int l,
                                             bf16_t* As, bf16_t* Bs,  // each [2][128*64]
                                             f32x4 acc[4][4]) {
    const int wr = w >> 1, wc = w & 1;
    const int r8 = l >> 3;
    const int sc = ((l & 7) ^ r8) << 3;   // inverse-swizzled global col (rule #21)

#define STG8(buf, kt)                                                                      \
    {                                                                                      \
        _Pragma("unroll")                                                                  \
        for (int j = 0; j < 4; ++j) {                                                      \
            int rr = j * 32 + w * 8 + r8;                                                  \
            __builtin_amdgcn_global_load_lds(                                              \
                AS1C(A + (size_t)(rowA0 + rr) * 1024 + (kt) * 64 + sc),                    \
                AS3(As + (buf) * 8192 + (j * 32 + w * 8) * 64), 16, 0, 0);                 \
            __builtin_amdgcn_global_load_lds(                                              \
                AS1C(Bt + (size_t)(colB0 + rr) * 1024 + (kt) * 64 + sc),                   \
                AS3(Bs + (buf) * 8192 + (j * 32 + w * 8) * 64), 16, 0, 0);                 \
        }                                                                                  \
    }

    STG8(0, 0);
    for (int T = 0; T < 16; ++T) {
        if (T < 15) {
            STG8((T + 1) & 1, T + 1);
            asm volatile("s_waitcnt vmcnt(8)" ::: "memory");   // tile T landed; T+1 in flight
        } else {
            asm volatile("s_waitcnt vmcnt(0)" ::: "memory");
        }
        __builtin_amdgcn_s_barrier();
        const bf16_t* cA = As + (T & 1) * 8192;
        const bf16_t* cB = Bs + (T & 1) * 8192;
#pragma unroll
        for (int kk = 0; kk < 2; ++kk) {
            const int ec = (kk * 32 + (l >> 4) * 8) ^ ((l & 7) << 3);
            bf16x8 af[4], bfr[4];
#pragma unroll
            for (int mm = 0; mm < 4; ++mm)
                af[mm] = *reinterpret_cast<const bf16x8*>(
                    cA + (wr * 64 + mm * 16 + (l & 15)) * 64 + ec);
#pragma unroll
            for (int n = 0; n < 4; ++n)
                bfr[n] = *reinterpret_cast<const bf16x8*>(
                    cB + (wc * 64 + n * 16 + (l & 15)) * 64 + ec);
            asm volatile("s_waitcnt lgkmcnt(0)" ::: "memory");
            __builtin_amdgcn_sched_barrier(0);
            __builtin_amdgcn_s_setprio(1);
#pragma unroll
            for (int mm = 0; mm < 4; ++mm)
#pragma unroll
                for (int n = 0; n < 4; ++n)
                    acc[mm][n] = __builtin_amdgcn_mfma_f32_16x16x32_bf16(af[mm], bfr[n],
                                                                         acc[mm][n], 0, 0, 0);
            __builtin_amdgcn_s_setprio(0);
        }
        __builtin_amdgcn_s_barrier();   // all reads of buf[T&1] done -> safe to restage
    }
#undef STG8
}

// ---------------- GEMM1: qkv = xb @ w_qkv, persistent 3-tile blocks + RoPE epilogue ------
// R14: 512 persistent blocks (2/CU, one residency round). Block (by, bxb) computes the
// q, k, v tiles at (by, bxb), (by, bxb+8), (by, bxb+16) sequentially -> the 256 KB
// A-panel is re-read from L2 (same CU/XCD) for tiles 2 and 3 instead of from HBM.
// q is pre-scaled by log2e/64 so attention's softmax is exp2(s - SHIFT) directly.
__global__ __launch_bounds__(256, 2) void k_gemm_qkv(const bf16_t* __restrict__ A,
                                                     const bf16_t* __restrict__ Bt,
                                                     const float* __restrict__ cosT,
                                                     const float* __restrict__ sinT,
                                                     bf16_t* __restrict__ qb,
                                                     bf16_t* __restrict__ kb,
                                                     bf16_t* __restrict__ vb) {
    __shared__ alignas(128) char smem[65536];
    bf16_t* As = (bf16_t*)smem;
    bf16_t* Bs = (bf16_t*)(smem + 32768);
    const int tid = threadIdx.x, w = tid >> 6, l = tid & 63;
    const int wr = w >> 1, wc = w & 1;
    const int p = blockIdx.x;                   // 0..511
    const int xcd = p & 7, idx = p >> 3;        // 64 blocks per XCD
    const int by = xcd * 8 + (idx & 7);         // 0..63 (contiguous 8 per XCD)
    const int bxb = idx >> 3;                   // 0..7
    const int rowA0 = by * 128;

    for (int part = 0; part < 3; ++part) {
        const int colB0 = part * 1024 + bxb * 128;

        f32x4 acc[4][4] = {};
        gemm128_pipe(A, Bt, rowA0, colB0, w, l, As, Bs, acc);

        if (part == 2) {
            // ---- v: transpose via LDS, coalesced (dh, L) stores ----
            __builtin_amdgcn_sched_barrier(0);
            __syncthreads();
            bf16_t* Tb = (bf16_t*)smem;  // [128][136]
#pragma unroll
            for (int m = 0; m < 4; ++m)
#pragma unroll
                for (int n = 0; n < 4; ++n) {
                    int cc = wc * 64 + n * 16 + (l & 15);
                    int rr = wr * 64 + m * 16 + (l >> 4) * 4;
#pragma unroll
                    for (int r = 0; r < 4; ++r)
                        Tb[cc * 136 + rr + r] = (bf16_t)acc[m][n][r];
                }
            __syncthreads();
            const int j = tid >> 1, half = tid & 1;
            const int c = colB0 + j;
            const int head = (c & 1023) >> 6, d = c & 63;
            const int bb = rowA0 >> 10, ll0 = rowA0 & 1023;
            bf16_t* dst = vb + (((size_t)bb * 16 + head) * 64 + d) * 1024 + ll0 + half * 64;
            const bf16_t* srcp = Tb + j * 136 + half * 64;
#pragma unroll
            for (int e = 0; e < 8; ++e)
                *reinterpret_cast<bf16x8*>(dst + e * 8) =
                    *reinterpret_cast<const bf16x8*>(srcp + e * 8);
        } else {
            bf16_t* dstb = (part == 0) ? qb : kb;
            const float qscl = (part == 0) ? (1.4426950408889634f / 64.0f) : 1.0f;
#pragma unroll
            for (int m = 0; m < 4; ++m)
#pragma unroll
                for (int n = 0; n < 4; ++n) {
                    const int c = colB0 + wc * 64 + n * 16 + (l & 15);
                    const int head = (c & 1023) >> 6;
                    const int d = c & 63;
                    const int rbase = rowA0 + wr * 64 + m * 16 + (l >> 4) * 4;
#pragma unroll
                    for (int r = 0; r < 4; ++r) {
                        int row = rbase + r;
                        int bb = row >> 10, ll = row & 1023;
                        float v0 = acc[m][n][r];
                        float vp = __shfl_xor(v0, 1, 64);
                        float cs = cosT[ll * 64 + d];
                        float sn = sinT[ll * 64 + d];
                        float res = (d & 1) ? fmaf(vp, sn, v0 * cs) : fmaf(-vp, sn, v0 * cs);
                        dstb[(((size_t)bb * 16 + head) * 1024 + ll) * 64 + d] = (bf16_t)(res * qscl);
                    }
                }
            __syncthreads();   // all waves past LDS reads before next part restages
        }
    }
}

// ---------------- GEMM2: out = ob @ w_proj, 128^2 pipelined core, f32 epilogue ----------
__global__ __launch_bounds__(256, 2) void k_gemm_out(const bf16_t* __restrict__ A,
                                                     const bf16_t* __restrict__ Bt,
                                                     float* __restrict__ out) {
    __shared__ alignas(128) char smem[65536];
    bf16_t* As = (bf16_t*)smem;
    bf16_t* Bs = (bf16_t*)(smem + 32768);
    const int tid = threadIdx.x, w = tid >> 6, l = tid & 63;
    const int wr = w >> 1, wc = w & 1;
    const int bid = blockIdx.x;                 // 0..511
    const int xcd = bid & 7, idx = bid >> 3;    // 64 blocks per XCD
    const int by = (xcd >> 1) * 16 + (idx & 15);
    const int bx = (xcd & 1) * 4 + (idx >> 4);
    const int rowA0 = by * 128, colB0 = bx * 128;

    f32x4 acc[4][4] = {};
    gemm128_pipe(A, Bt, rowA0, colB0, w, l, As, Bs, acc);

#pragma unroll
    for (int m = 0; m < 4; ++m)
#pragma unroll
        for (int n = 0; n < 4; ++n) {
            int c = colB0 + wc * 64 + n * 16 + (l & 15);
            int rbase = rowA0 + wr * 64 + m * 16 + (l >> 4) * 4;
#pragma unroll
            for (int r = 0; r < 4; ++r)
                out[(size_t)(rbase + r) * 1024 + c] = acc[m][n][r];
        }
}

// ---------------- flash attention v6: 4-wave blocks, high occupancy (R9-proven) ----------
// Q-block 128, 4 waves x 32 rows. Swapped QK^T in-reg softmax; fixed-shift exp2(s-4).
__global__ __launch_bounds__(256, 4) void k_attn(const bf16_t* __restrict__ qb,
                                                 const bf16_t* __restrict__ kb,
                                                 const bf16_t* __restrict__ vb,
                                                 bf16_t* __restrict__ ob) {
    __shared__ alignas(128) bf16_t Ks[2][64 * 64];
    __shared__ alignas(128) bf16_t Vs[2][64 * 64];
    const int tid = threadIdx.x, w = tid >> 6, l = tid & 63;
    const int g = l >> 4;
    const int bid = blockIdx.x;                    // 0..1023
    const int bs = (bid & 7) * 128 + (bid >> 3);   // XCD-aware bijective swizzle
    const int bh = bs >> 3, bi = bh >> 4, h = bh & 15;
    const int q0 = (bs & 7) * 128;
    const bf16_t* qbase = qb + (size_t)bh * 1024 * 64;
    const bf16_t* kbase = kb + (size_t)bh * 1024 * 64;
    const bf16_t* vbase = vb + (size_t)bh * 64 * 1024;

    bf16x8 qf[2][2];
#pragma unroll
    for (int m = 0; m < 2; ++m) {
        int qrow = q0 + w * 32 + m * 16 + (l & 15);
#pragma unroll
        for (int kk = 0; kk < 2; ++kk)
            qf[m][kk] = *reinterpret_cast<const bf16x8*>(
                qbase + (size_t)qrow * 64 + kk * 32 + g * 8);
    }

    float l_run[2] = {0.f, 0.f};
    f32x4 o_acc[2][4] = {};

    const int srow = l >> 3;
    const int sc = 8 * ((l & 7) ^ srow);
#define STAGE(buf, kv0)                                                                   \
    {                                                                                     \
        _Pragma("unroll")                                                                 \
        for (int i = 0; i < 2; ++i) {                                                     \
            int rr = w * 16 + i * 8 + srow;                                               \
            __builtin_amdgcn_global_load_lds(AS1C(kbase + (size_t)((kv0) + rr) * 64 + sc),\
                                             AS3(&Ks[buf][(w * 16 + i * 8) * 64]), 16, 0, 0); \
            __builtin_amdgcn_global_load_lds(AS1C(vbase + (size_t)rr * 1024 + (kv0) + sc),\
                                             AS3(&Vs[buf][(w * 16 + i * 8) * 64]), 16, 0, 0); \
        }                                                                                 \
    }

    STAGE(0, 0);
    __syncthreads();

    const float SHIFT = 4.0f;   // fixed shift; q pre-scaled so S is already in log2 units
    int cur = 0;
    for (int t = 0; t < 16; ++t) {
        if (t < 15) STAGE(cur ^ 1, (t + 1) * 64);

        f32x4 sacc[2][4] = {};
#pragma unroll
        for (int kk = 0; kk < 2; ++kk)
#pragma unroll
            for (int n = 0; n < 4; ++n) {
                int rr = n * 16 + (l & 15);
                int ec = (kk * 32 + g * 8) ^ ((l & 7) << 3);
                bf16x8 kfr = *reinterpret_cast<const bf16x8*>(&Ks[cur][rr * 64 + ec]);
                sacc[0][n] = __builtin_amdgcn_mfma_f32_16x16x32_bf16(kfr, qf[0][kk], sacc[0][n], 0, 0, 0);
                sacc[1][n] = __builtin_amdgcn_mfma_f32_16x16x32_bf16(kfr, qf[1][kk], sacc[1][n], 0, 0, 0);
            }

        s16x4 pa[2][4];
#pragma unroll
        for (int m = 0; m < 2; ++m) {
            float lsum = 0.f;
#pragma unroll
            for (int n = 0; n < 4; ++n) {
                bf16x4 pb;
#pragma unroll
                for (int r = 0; r < 4; ++r) {
                    float pv = fast_exp2(sacc[m][n][r] - SHIFT);
                    lsum += pv;
                    pb[r] = (bf16_t)pv;
                }
                pa[m][n] = __builtin_bit_cast(s16x4, pb);
            }
            l_run[m] += lsum;
        }

        const char* vrow = (const char*)&Vs[cur][0] + (l & 15) * 128;
#pragma unroll
        for (int c = 0; c < 4; ++c) {
            int kvb = (c * 32 + g * 8) ^ ((l & 7) << 4);
#pragma unroll
            for (int nd = 0; nd < 4; ++nd) {
                s16x4 vf = *reinterpret_cast<const s16x4*>(vrow + nd * 2048 + kvb);
                o_acc[0][nd] = __builtin_amdgcn_mfma_f32_16x16x16bf16_1k(pa[0][c], vf, o_acc[0][nd], 0, 0, 0);
                o_acc[1][nd] = __builtin_amdgcn_mfma_f32_16x16x16bf16_1k(pa[1][c], vf, o_acc[1][nd], 0, 0, 0);
            }
        }
        __syncthreads();
        cur ^= 1;
    }

#pragma unroll
    for (int m = 0; m < 2; ++m) {
        float ls = l_run[m];
        ls += __shfl_xor(ls, 16, 64);
        ls += __shfl_xor(ls, 32, 64);
        float inv = 1.0f / ls;
#pragma unroll
        for (int r = 0; r < 4; ++r) {
            float c2 = __shfl(inv, (l & 48) | (g * 4 + r), 64);
            int row = q0 + w * 32 + m * 16 + g * 4 + r;
#pragma unroll
            for (int n = 0; n < 4; ++n)
                ob[((size_t)bi * 1024 + row) * 1024 + h * 64 + n * 16 + (l & 15)] =
                    (bf16_t)(o_acc[m][n][r] * c2);
        }
    }
#undef STAGE
}

extern "C" void kernel_launch(void* const* d_in, const int* in_sizes, int n_in,
                              void* d_out, int out_size, void* d_ws, size_t ws_size,
                              hipStream_t stream) {
    (void)in_sizes; (void)n_in; (void)out_size; (void)ws_size;
    const float* x     = (const float*)d_in[0];
    const float* wqkv  = (const float*)d_in[1];
    const float* wproj = (const float*)d_in[2];
    char* ws = (char*)d_ws;

    bf16_t* xb  = (bf16_t*)(ws);
    bf16_t* wqT = (bf16_t*)(ws + 16777216ull);
    bf16_t* wpT = (bf16_t*)(ws + 23068672ull);
    bf16_t* qb  = (bf16_t*)(ws + 25165824ull);
    bf16_t* kb  = (bf16_t*)(ws + 41943040ull);
    bf16_t* vb  = (bf16_t*)(ws + 58720256ull);
    bf16_t* ob  = (bf16_t*)(ws + 75497472ull);
    float*  cosT = (float*)(ws + 92274688ull);
    float*  sinT = (float*)(ws + 92536832ull);

    k_prep<<<9472, 256, 0, stream>>>(x, wqkv, wproj, xb, wqT, wpT, cosT, sinT);
    k_gemm_qkv<<<512, 256, 0, stream>>>(xb, wqT, cosT, sinT, qb, kb, vb);
    k_attn<<<1024, 256, 0, stream>>>(qb, kb, vb, ob);
    k_gemm_out<<<512, 256, 0, stream>>>(ob, wpT, (float*)d_out);
}

// Round 16
// 152.553 us; speedup vs baseline: 1.3784x; 1.3784x over previous
//
#include <hip/hip_runtime.h>
#include <hip/hip_bf16.h>
#include <math.h>

typedef __bf16 bf16_t;
typedef __attribute__((ext_vector_type(8))) __bf16 bf16x8;
typedef __attribute__((ext_vector_type(4))) __bf16 bf16x4;
typedef __attribute__((ext_vector_type(4))) short s16x4;
typedef __attribute__((ext_vector_type(4))) float f32x4;

#define AS1C(p) ((const __attribute__((address_space(1))) void*)(p))
#define AS3(p)  ((__attribute__((address_space(3))) void*)(p))

__device__ __forceinline__ float fast_exp2(float x) { return __builtin_amdgcn_exp2f(x); }

// ------------- transpose+convert body: in (R x C f32) -> out (C x R bf16) -------------
__device__ __forceinline__ void tconv_body(const float* __restrict__ in,
                                           bf16_t* __restrict__ out, int R, int C,
                                           int r0, int c0, float (*tile)[65], int tid) {
#pragma unroll
    for (int i = 0; i < 16; ++i) {
        int e = i * 256 + tid;
        int r = e >> 6, c = e & 63;
        tile[r][c] = in[(size_t)(r0 + r) * C + c0 + c];
    }
    __syncthreads();
#pragma unroll
    for (int i = 0; i < 16; ++i) {
        int e = i * 256 + tid;
        int c = e >> 6, r = e & 63;
        out[(size_t)(c0 + c) * R + r0 + r] = (bf16_t)tile[r][c];
    }
}

// ---------------- fused prep: cvt(x) | tconv(wqkv) | tconv(wproj) | RoPE tables ----------
__global__ __launch_bounds__(256) void k_prep(const float* __restrict__ x,
                                              const float* __restrict__ wqkv,
                                              const float* __restrict__ wproj,
                                              bf16_t* __restrict__ xb,
                                              bf16_t* __restrict__ wqT,
                                              bf16_t* __restrict__ wpT,
                                              float* __restrict__ cosT,
                                              float* __restrict__ sinT) {
    __shared__ float tile[64][65];
    const int bid = blockIdx.x, tid = threadIdx.x;
    if (bid < 8192) {
        int i = bid * 256 + tid;
        float4 v = reinterpret_cast<const float4*>(x)[i];
        bf16x4 o;
        o[0] = (bf16_t)v.x; o[1] = (bf16_t)v.y; o[2] = (bf16_t)v.z; o[3] = (bf16_t)v.w;
        reinterpret_cast<bf16x4*>(xb)[i] = o;
    } else if (bid < 8960) {
        int t = bid - 8192;                    // 768 = 48 cx * 16 ry
        tconv_body(wqkv, wqT, 1024, 3072, (t / 48) * 64, (t % 48) * 64, tile, tid);
    } else if (bid < 9216) {
        int t = bid - 8960;                    // 256 = 16 cx * 16 ry
        tconv_body(wproj, wpT, 1024, 1024, (t / 16) * 64, (t % 16) * 64, tile, tid);
    } else {
        int i = (bid - 9216) * 256 + tid;      // 65536 table entries
        int l = i >> 6, d = i & 63;
        int hh = l >> 5, ww = l & 31;          // H = W = 32
        float pos = (d < 32) ? (-1.0f + (2.0f / 31.0f) * (float)hh)
                             : (-1.0f + (2.0f / 31.0f) * (float)ww);
        int fi = (d & 31) >> 1;
        float fb = (1.0f + (127.0f / 15.0f) * (float)fi) * 3.14159265358979323846f;
        float fr = pos * fb;
        cosT[i] = cosf(fr);
        sinT[i] = sinf(fr);
    }
}

// ---------------- 128x128 double-buffered pipelined GEMM core (K=1024) ----------------
// 4 waves (2M x 2N), per-wave 64x64 (acc[4][4]). 64 KiB LDS -> 2 blocks/CU.
// Counted vmcnt(8) depth-1 prefetch, 2 barriers/tile, T2 swizzle (conflict-free reads).
__device__ __forceinline__ void gemm128_pipe(const bf16_t* __restrict__ A,
                                             const bf16_t* __restrict__ Bt,
                                             int rowA0, int colB0, int w, int l,
                                             bf16_t* As, bf16_t* Bs,  // each [2][128*64]
                                             f32x4 acc[4][4]) {
    const int wr = w >> 1, wc = w & 1;
    const int r8 = l >> 3;
    const int sc = ((l & 7) ^ r8) << 3;   // inverse-swizzled global col (rule #21)

#define STG8(buf, kt)                                                                      \
    {                                                                                      \
        _Pragma("unroll")                                                                  \
        for (int j = 0; j < 4; ++j) {                                                      \
            int rr = j * 32 + w * 8 + r8;                                                  \
            __builtin_amdgcn_global_load_lds(                                              \
                AS1C(A + (size_t)(rowA0 + rr) * 1024 + (kt) * 64 + sc),                    \
                AS3(As + (buf) * 8192 + (j * 32 + w * 8) * 64), 16, 0, 0);                 \
            __builtin_amdgcn_global_load_lds(                                              \
                AS1C(Bt + (size_t)(colB0 + rr) * 1024 + (kt) * 64 + sc),                   \
                AS3(Bs + (buf) * 8192 + (j * 32 + w * 8) * 64), 16, 0, 0);                 \
        }                                                                                  \
    }

    STG8(0, 0);
    for (int T = 0; T < 16; ++T) {
        if (T < 15) {
            STG8((T + 1) & 1, T + 1);
            asm volatile("s_waitcnt vmcnt(8)" ::: "memory");   // tile T landed; T+1 in flight
        } else {
            asm volatile("s_waitcnt vmcnt(0)" ::: "memory");
        }
        __builtin_amdgcn_s_barrier();
        const bf16_t* cA = As + (T & 1) * 8192;
        const bf16_t* cB = Bs + (T & 1) * 8192;
#pragma unroll
        for (int kk = 0; kk < 2; ++kk) {
            const int ec = (kk * 32 + (l >> 4) * 8) ^ ((l & 7) << 3);
            bf16x8 af[4], bfr[4];
#pragma unroll
            for (int mm = 0; mm < 4; ++mm)
                af[mm] = *reinterpret_cast<const bf16x8*>(
                    cA + (wr * 64 + mm * 16 + (l & 15)) * 64 + ec);
#pragma unroll
            for (int n = 0; n < 4; ++n)
                bfr[n] = *reinterpret_cast<const bf16x8*>(
                    cB + (wc * 64 + n * 16 + (l & 15)) * 64 + ec);
            asm volatile("s_waitcnt lgkmcnt(0)" ::: "memory");
            __builtin_amdgcn_sched_barrier(0);
            __builtin_amdgcn_s_setprio(1);
#pragma unroll
            for (int mm = 0; mm < 4; ++mm)
#pragma unroll
                for (int n = 0; n < 4; ++n)
                    acc[mm][n] = __builtin_amdgcn_mfma_f32_16x16x32_bf16(af[mm], bfr[n],
                                                                         acc[mm][n], 0, 0, 0);
            __builtin_amdgcn_s_setprio(0);
        }
        __builtin_amdgcn_s_barrier();   // all reads of buf[T&1] done -> safe to restage
    }
#undef STG8
}

// ---------------- GEMM1: qkv = xb @ w_qkv, 128^2 pipelined core + RoPE epilogue ----------
// q is pre-scaled by log2e/64 so attention's softmax is exp2(s - SHIFT) directly.
__global__ __launch_bounds__(256, 2) void k_gemm_qkv(const bf16_t* __restrict__ A,
                                                     const bf16_t* __restrict__ Bt,
                                                     const float* __restrict__ cosT,
                                                     const float* __restrict__ sinT,
                                                     bf16_t* __restrict__ qb,
                                                     bf16_t* __restrict__ kb,
                                                     bf16_t* __restrict__ vb) {
    __shared__ alignas(128) char smem[65536];
    bf16_t* As = (bf16_t*)smem;
    bf16_t* Bs = (bf16_t*)(smem + 32768);
    const int tid = threadIdx.x, w = tid >> 6, l = tid & 63;
    const int wr = w >> 1, wc = w & 1;
    const int bid = blockIdx.x;                 // 0..1535
    const int xcd = bid & 7, idx = bid >> 3;    // 192 blocks per XCD
    const int by = (xcd >> 1) * 16 + (idx & 15);
    const int bx = (xcd & 1) * 12 + (idx >> 4);
    const int rowA0 = by * 128, colB0 = bx * 128;

    f32x4 acc[4][4] = {};
    gemm128_pipe(A, Bt, rowA0, colB0, w, l, As, Bs, acc);

    const int part = colB0 >> 10;   // bx 0-7 -> q, 8-15 -> k, 16-23 -> v
    if (part == 2) {
        // ---- v: transpose via LDS, coalesced (dh, L) stores ----
        __builtin_amdgcn_sched_barrier(0);
        __syncthreads();
        bf16_t* Tb = (bf16_t*)smem;  // [128][136]
#pragma unroll
        for (int m = 0; m < 4; ++m)
#pragma unroll
            for (int n = 0; n < 4; ++n) {
                int cc = wc * 64 + n * 16 + (l & 15);
                int rr = wr * 64 + m * 16 + (l >> 4) * 4;
#pragma unroll
                for (int r = 0; r < 4; ++r)
                    Tb[cc * 136 + rr + r] = (bf16_t)acc[m][n][r];
            }
        __syncthreads();
        const int j = tid >> 1, half = tid & 1;
        const int c = colB0 + j;
        const int head = (c & 1023) >> 6, d = c & 63;
        const int bb = rowA0 >> 10, ll0 = rowA0 & 1023;
        bf16_t* dst = vb + (((size_t)bb * 16 + head) * 64 + d) * 1024 + ll0 + half * 64;
        const bf16_t* srcp = Tb + j * 136 + half * 64;
#pragma unroll
        for (int e = 0; e < 8; ++e)
            *reinterpret_cast<bf16x8*>(dst + e * 8) =
                *reinterpret_cast<const bf16x8*>(srcp + e * 8);
    } else {
        bf16_t* dstb = (part == 0) ? qb : kb;
        const float qscl = (part == 0) ? (1.4426950408889634f / 64.0f) : 1.0f;
#pragma unroll
        for (int m = 0; m < 4; ++m)
#pragma unroll
            for (int n = 0; n < 4; ++n) {
                const int c = colB0 + wc * 64 + n * 16 + (l & 15);
                const int head = (c & 1023) >> 6;
                const int d = c & 63;
                const int rbase = rowA0 + wr * 64 + m * 16 + (l >> 4) * 4;
#pragma unroll
                for (int r = 0; r < 4; ++r) {
                    int row = rbase + r;
                    int bb = row >> 10, ll = row & 1023;
                    float v0 = acc[m][n][r];
                    float vp = __shfl_xor(v0, 1, 64);
                    float cs = cosT[ll * 64 + d];
                    float sn = sinT[ll * 64 + d];
                    float res = (d & 1) ? fmaf(vp, sn, v0 * cs) : fmaf(-vp, sn, v0 * cs);
                    dstb[(((size_t)bb * 16 + head) * 1024 + ll) * 64 + d] = (bf16_t)(res * qscl);
                }
            }
    }
}

// ---------------- GEMM2: out = ob @ w_proj, 128^2 pipelined core, f32 epilogue ----------
__global__ __launch_bounds__(256, 2) void k_gemm_out(const bf16_t* __restrict__ A,
                                                     const bf16_t* __restrict__ Bt,
                                                     float* __restrict__ out) {
    __shared__ alignas(128) char smem[65536];
    bf16_t* As = (bf16_t*)smem;
    bf16_t* Bs = (bf16_t*)(smem + 32768);
    const int tid = threadIdx.x, w = tid >> 6, l = tid & 63;
    const int wr = w >> 1, wc = w & 1;
    const int bid = blockIdx.x;                 // 0..511
    const int xcd = bid & 7, idx = bid >> 3;    // 64 blocks per XCD
    const int by = (xcd >> 1) * 16 + (idx & 15);
    const int bx = (xcd & 1) * 4 + (idx >> 4);
    const int rowA0 = by * 128, colB0 = bx * 128;

    f32x4 acc[4][4] = {};
    gemm128_pipe(A, Bt, rowA0, colB0, w, l, As, Bs, acc);

#pragma unroll
    for (int m = 0; m < 4; ++m)
#pragma unroll
        for (int n = 0; n < 4; ++n) {
            int c = colB0 + wc * 64 + n * 16 + (l & 15);
            int rbase = rowA0 + wr * 64 + m * 16 + (l >> 4) * 4;
#pragma unroll
            for (int r = 0; r < 4; ++r)
                out[(size_t)(rbase + r) * 1024 + c] = acc[m][n][r];
        }
}

// ---------------- flash attention v6: 4-wave blocks, high occupancy (R9-proven) ----------
// Q-block 128, 4 waves x 32 rows. Swapped QK^T in-reg softmax; fixed-shift exp2(s-4).
__global__ __launch_bounds__(256, 4) void k_attn(const bf16_t* __restrict__ qb,
                                                 const bf16_t* __restrict__ kb,
                                                 const bf16_t* __restrict__ vb,
                                                 bf16_t* __restrict__ ob) {
    __shared__ alignas(128) bf16_t Ks[2][64 * 64];
    __shared__ alignas(128) bf16_t Vs[2][64 * 64];
    const int tid = threadIdx.x, w = tid >> 6, l = tid & 63;
    const int g = l >> 4;
    const int bid = blockIdx.x;                    // 0..1023
    const int bs = (bid & 7) * 128 + (bid >> 3);   // XCD-aware bijective swizzle
    const int bh = bs >> 3, bi = bh >> 4, h = bh & 15;
    const int q0 = (bs & 7) * 128;
    const bf16_t* qbase = qb + (size_t)bh * 1024 * 64;
    const bf16_t* kbase = kb + (size_t)bh * 1024 * 64;
    const bf16_t* vbase = vb + (size_t)bh * 64 * 1024;

    bf16x8 qf[2][2];
#pragma unroll
    for (int m = 0; m < 2; ++m) {
        int qrow = q0 + w * 32 + m * 16 + (l & 15);
#pragma unroll
        for (int kk = 0; kk < 2; ++kk)
            qf[m][kk] = *reinterpret_cast<const bf16x8*>(
                qbase + (size_t)qrow * 64 + kk * 32 + g * 8);
    }

    float l_run[2] = {0.f, 0.f};
    f32x4 o_acc[2][4] = {};

    const int srow = l >> 3;
    const int sc = 8 * ((l & 7) ^ srow);
#define STAGE(buf, kv0)                                                                   \
    {                                                                                     \
        _Pragma("unroll")                                                                 \
        for (int i = 0; i < 2; ++i) {                                                     \
            int rr = w * 16 + i * 8 + srow;                                               \
            __builtin_amdgcn_global_load_lds(AS1C(kbase + (size_t)((kv0) + rr) * 64 + sc),\
                                             AS3(&Ks[buf][(w * 16 + i * 8) * 64]), 16, 0, 0); \
            __builtin_amdgcn_global_load_lds(AS1C(vbase + (size_t)rr * 1024 + (kv0) + sc),\
                                             AS3(&Vs[buf][(w * 16 + i * 8) * 64]), 16, 0, 0); \
        }                                                                                 \
    }

    STAGE(0, 0);
    __syncthreads();

    const float SHIFT = 4.0f;   // fixed shift; q pre-scaled so S is already in log2 units
    int cur = 0;
    for (int t = 0; t < 16; ++t) {
        if (t < 15) STAGE(cur ^ 1, (t + 1) * 64);

        f32x4 sacc[2][4] = {};
#pragma unroll
        for (int kk = 0; kk < 2; ++kk)
#pragma unroll
            for (int n = 0; n < 4; ++n) {
                int rr = n * 16 + (l & 15);
                int ec = (kk * 32 + g * 8) ^ ((l & 7) << 3);
                bf16x8 kfr = *reinterpret_cast<const bf16x8*>(&Ks[cur][rr * 64 + ec]);
                sacc[0][n] = __builtin_amdgcn_mfma_f32_16x16x32_bf16(kfr, qf[0][kk], sacc[0][n], 0, 0, 0);
                sacc[1][n] = __builtin_amdgcn_mfma_f32_16x16x32_bf16(kfr, qf[1][kk], sacc[1][n], 0, 0, 0);
            }

        s16x4 pa[2][4];
#pragma unroll
        for (int m = 0; m < 2; ++m) {
            float lsum = 0.f;
#pragma unroll
            for (int n = 0; n < 4; ++n) {
                bf16x4 pb;
#pragma unroll
                for (int r = 0; r < 4; ++r) {
                    float pv = fast_exp2(sacc[m][n][r] - SHIFT);
                    lsum += pv;
                    pb[r] = (bf16_t)pv;
                }
                pa[m][n] = __builtin_bit_cast(s16x4, pb);
            }
            l_run[m] += lsum;
        }

        const char* vrow = (const char*)&Vs[cur][0] + (l & 15) * 128;
#pragma unroll
        for (int c = 0; c < 4; ++c) {
            int kvb = (c * 32 + g * 8) ^ ((l & 7) << 4);
#pragma unroll
            for (int nd = 0; nd < 4; ++nd) {
                s16x4 vf = *reinterpret_cast<const s16x4*>(vrow + nd * 2048 + kvb);
                o_acc[0][nd] = __builtin_amdgcn_mfma_f32_16x16x16bf16_1k(pa[0][c], vf, o_acc[0][nd], 0, 0, 0);
                o_acc[1][nd] = __builtin_amdgcn_mfma_f32_16x16x16bf16_1k(pa[1][c], vf, o_acc[1][nd], 0, 0, 0);
            }
        }
        __syncthreads();
        cur ^= 1;
    }

#pragma unroll
    for (int m = 0; m < 2; ++m) {
        float ls = l_run[m];
        ls += __shfl_xor(ls, 16, 64);
        ls += __shfl_xor(ls, 32, 64);
        float inv = 1.0f / ls;
#pragma unroll
        for (int r = 0; r < 4; ++r) {
            float c2 = __shfl(inv, (l & 48) | (g * 4 + r), 64);
            int row = q0 + w * 32 + m * 16 + g * 4 + r;
#pragma unroll
            for (int n = 0; n < 4; ++n)
                ob[((size_t)bi * 1024 + row) * 1024 + h * 64 + n * 16 + (l & 15)] =
                    (bf16_t)(o_acc[m][n][r] * c2);
        }
    }
#undef STAGE
}

extern "C" void kernel_launch(void* const* d_in, const int* in_sizes, int n_in,
                              void* d_out, int out_size, void* d_ws, size_t ws_size,
                              hipStream_t stream) {
    (void)in_sizes; (void)n_in; (void)out_size; (void)ws_size;
    const float* x     = (const float*)d_in[0];
    const float* wqkv  = (const float*)d_in[1];
    const float* wproj = (const float*)d_in[2];
    char* ws = (char*)d_ws;

    bf16_t* xb  = (bf16_t*)(ws);
    bf16_t* wqT = (bf16_t*)(ws + 16777216ull);
    bf16_t* wpT = (bf16_t*)(ws + 23068672ull);
    bf16_t* qb  = (bf16_t*)(ws + 25165824ull);
    bf16_t* kb  = (bf16_t*)(ws + 41943040ull);
    bf16_t* vb  = (bf16_t*)(ws + 58720256ull);
    bf16_t* ob  = (bf16_t*)(ws + 75497472ull);
    float*  cosT = (float*)(ws + 92274688ull);
    float*  sinT = (float*)(ws + 92536832ull);

    k_prep<<<9472, 256, 0, stream>>>(x, wqkv, wproj, xb, wqT, wpT, cosT, sinT);
    k_gemm_qkv<<<1536, 256, 0, stream>>>(xb, wqT, cosT, sinT, qb, kb, vb);
    k_attn<<<1024, 256, 0, stream>>>(qb, kb, vb, ob);
    k_gemm_out<<<512, 256, 0, stream>>>(ob, wpT, (float*)d_out);
}